// Round 11
// baseline (103686.084 us; speedup 1.0000x reference)
//
#include <hip/hip_runtime.h>
#include <hip/hip_bf16.h>
#include <math.h>

#define T_ 256
#define B_ 128
#define VOC_ 256
#define EMB_ 512
#define N_ 1024
#define H_ 2048
#define WIN_ 32
#define OUT_EMB_ 1024

typedef _Float16 half8 __attribute__((ext_vector_type(8)));
typedef float f32x4 __attribute__((ext_vector_type(4)));

__device__ __forceinline__ float sigmoidf_(float x) { return 1.f / (1.f + expf(-x)); }

#define MFMA16(A, B, C) __builtin_amdgcn_mfma_f32_16x16x32_f16((A), (B), (C), 0, 0, 0)

// ---------------------------------------------------------------------------
// Grid barrier via flag array, for a fully-resident normal launch (256 blocks
// on 256 CUs).  Block i release-stores flags[i]=tgt; every thread
// acquire-spins on flags[tid] (256 threads <-> 256 blocks).  tgt is strictly
// increasing within one call; flags are zeroed by the per-call memset.
// ---------------------------------------------------------------------------
__device__ __forceinline__ void gbar(unsigned* flags, unsigned tgt)
{
    __syncthreads();
    __threadfence();                      // publish all block writes device-wide
    if (threadIdx.x == 0)
        __hip_atomic_store(&flags[blockIdx.x], tgt, __ATOMIC_RELEASE,
                           __HIP_MEMORY_SCOPE_AGENT);
    unsigned v;
    do {
        v = __hip_atomic_load(&flags[threadIdx.x], __ATOMIC_ACQUIRE,
                              __HIP_MEMORY_SCOPE_AGENT);
        if (v < tgt) __builtin_amdgcn_s_sleep(8);
    } while (v < tgt);
    __threadfence();                      // discard stale cached lines
    __syncthreads();
}

// ---------------------------------------------------------------------------
// LSTM gate epilogue (R4-proven): lanes (l15&3)==0 own j; neighbor lanes hold
// the f,i,o,m quad, exchanged via shfl_xor.
// ---------------------------------------------------------------------------
__device__ __forceinline__ void lstm_epi(f32x4 acc, int rbase, bool owner, int jglob,
                                         float bfv, float biv, float bov, float bmv,
                                         float* __restrict__ c, _Float16* __restrict__ h,
                                         _Float16* __restrict__ ringSlot, int rhalf)
{
    #pragma unroll
    for (int jr = 0; jr < 4; ++jr) {
        float v  = acc[jr];
        float v1 = __shfl_xor(v, 1);
        float v2 = __shfl_xor(v, 2);
        float v3 = __shfl_xor(v, 3);
        if (owner) {
            const int row = rbase + jr;
            float f  = sigmoidf_(v  + bfv);
            float ii = sigmoidf_(v1 + biv);
            float o  = sigmoidf_(v2 + bov);
            float m  = tanhf(v3 + bmv);
            const int ci = row * 1024 + jglob;
            float cn = c[ci] * f + m * ii;
            float hn = tanhf(cn) * o;
            c[ci] = cn;
            h[ci] = (_Float16)hn;
            ringSlot[row * 2048 + rhalf + jglob] = (_Float16)hn;
        }
    }
}

// ---------------------------------------------------------------------------
// Fused LSTM GEMM, R4-proven LDS-staged pipeline, geometry 128x16 per block
// (bn = blockIdx: 256 x 16 gate-interleaved cols; 4 waves m-split 32 rows
// each).  WT row-major gate-interleaved [4096][Ktot] (R4-proven layout).
// BK=64, 2-deep register prefetch + double-buffered LDS.  Zero B-duplication.
// ---------------------------------------------------------------------------
__device__ __forceinline__
void lstm_gemm_body(_Float16 (*As)[128][72], _Float16 (*Bs)[16][72], int bn,
                    const _Float16* __restrict__ A0, int k0, int lda0,
                    const _Float16* __restrict__ A1, int k1, int lda1,
                    const _Float16* __restrict__ A2, int k2, int lda2,
                    const _Float16* __restrict__ WT, int Ktot,
                    const float* __restrict__ bias,
                    float* __restrict__ c, _Float16* __restrict__ hH,
                    _Float16* __restrict__ ringSlot, int ringHalf)
{
    const int tid = threadIdx.x;
    const int l = tid & 63, w = tid >> 6;
    const int l15 = l & 15, kg = l >> 4;

    // staging coords: A 128 rows x 64 k (4 half8/thread); B 16 x 64 (tid<128)
    const int arow = tid >> 2, akh = (tid & 3) * 16;
    const int brow = (tid >> 3) & 15, bkh = (tid & 7) * 8;
    const _Float16* Bg = WT + (size_t)(bn * 16 + brow) * Ktot;

    const int NIT = Ktot >> 6;           // 56 or 32 — always even

    f32x4 ac0 = {0.f, 0.f, 0.f, 0.f}, ac1 = {0.f, 0.f, 0.f, 0.f};

    half8 a0A, a1A, a2A, a3A, bA, a0B, a1B, a2B, a3B, bB;

    auto issue = [&](int it, half8& r0, half8& r1, half8& r2, half8& r3, half8& rb) {
        const int kb = it * 64;
        const _Float16* Ag; int so, ld;
        if (kb < k0)           { Ag = A0; so = 0;       ld = lda0; }
        else if (kb < k0 + k1) { Ag = A1; so = k0;      ld = lda1; }
        else                   { Ag = A2; so = k0 + k1; ld = lda2; }
        const _Float16* ap  = Ag + (size_t)arow * ld + (kb - so);
        const _Float16* ap2 = Ag + (size_t)(arow + 64) * ld + (kb - so);
        r0 = *(const half8*)(ap + akh);
        r1 = *(const half8*)(ap + akh + 8);
        r2 = *(const half8*)(ap2 + akh);
        r3 = *(const half8*)(ap2 + akh + 8);
        if (tid < 128) rb = *(const half8*)(Bg + kb + bkh);
    };
    auto wlds = [&](int buf, half8 r0, half8 r1, half8 r2, half8 r3, half8 rb) {
        *(half8*)&As[buf][arow][akh]          = r0;
        *(half8*)&As[buf][arow][akh + 8]      = r1;
        *(half8*)&As[buf][arow + 64][akh]     = r2;
        *(half8*)&As[buf][arow + 64][akh + 8] = r3;
        if (tid < 128) *(half8*)&Bs[buf][brow][bkh] = rb;
    };
    auto comp = [&](int buf) {
        #pragma unroll
        for (int ks = 0; ks < 2; ++ks) {
            half8 a0 = *(half8*)&As[buf][w * 32 + l15][ks * 32 + kg * 8];
            half8 a1 = *(half8*)&As[buf][w * 32 + 16 + l15][ks * 32 + kg * 8];
            half8 b0 = *(half8*)&Bs[buf][l15][ks * 32 + kg * 8];
            ac0 = MFMA16(a0, b0, ac0);
            ac1 = MFMA16(a1, b0, ac1);
        }
    };

    // prologue: tiles 0,1 in flight; tile 0 -> LDS[0]   (R4-proven schedule)
    issue(0, a0A, a1A, a2A, a3A, bA);
    issue(1, a0B, a1B, a2B, a3B, bB);
    wlds(0, a0A, a1A, a2A, a3A, bA);
    __syncthreads();

    for (int it = 0; it < NIT; it += 2) {
        comp(0);
        if (it + 2 < NIT) issue(it + 2, a0A, a1A, a2A, a3A, bA);
        __syncthreads();
        wlds(1, a0B, a1B, a2B, a3B, bB);
        __syncthreads();
        comp(1);
        if (it + 3 < NIT) issue(it + 3, a0B, a1B, a2B, a3B, bB);
        __syncthreads();
        if (it + 2 < NIT) wlds(0, a0A, a1A, a2A, a3A, bA);
        __syncthreads();
    }

    // fused LSTM epilogue (R4-proven; C/D: col = l&15, row-in-frag = kg*4 + j)
    const int cgl = bn * 16 + l15;               // gate-interleaved global col
    const bool owner = (cgl & 3) == 0;
    const int jglob = cgl >> 2;
    float bf = 0.f, bi = 0.f, bo_ = 0.f, bm_ = 0.f;
    if (owner) {
        bf  = bias[jglob];
        bi  = bias[1024 + jglob];
        bo_ = bias[2048 + jglob];
        bm_ = bias[3072 + jglob];
    }
    lstm_epi(ac0, w * 32 + kg * 4,      owner, jglob, bf, bi, bo_, bm_,
             c, hH, ringSlot, ringHalf);
    lstm_epi(ac1, w * 32 + 16 + kg * 4, owner, jglob, bf, bi, bo_, bm_,
             c, hH, ringSlot, ringHalf);
}

// ---------------------------------------------------------------------------
// Attention body (R5-proven). Ring layout [slot][b][2048].
// ---------------------------------------------------------------------------
__device__ __forceinline__ void attn_body(float* hsl, float* pl, int b,
                                          const _Float16* __restrict__ ring, int t,
                                          _Float16* __restrict__ faH)
{
    const int tid = threadIdx.x;
    const _Float16* hs = ring + ((size_t)(t & 31) * B_ + b) * 2048;
    {
        half8 v = *(const half8*)(hs + tid * 8);
        #pragma unroll
        for (int e = 0; e < 8; ++e) hsl[tid * 8 + e] = (float)v[e];
    }
    __syncthreads();

    const int wv = tid >> 6, lane = tid & 63;
    #pragma unroll
    for (int w8 = 0; w8 < 8; ++w8) {
        const int w = wv * 8 + w8;
        const int tw = t - 31 + w;
        float s = 0.f;
        if (tw >= 0) {
            const _Float16* br = ring + ((size_t)(tw & 31) * B_ + b) * 2048;
            #pragma unroll
            for (int p2 = 0; p2 < 4; ++p2) {
                half8 v = *(const half8*)(br + p2 * 512 + lane * 8);
                const float* hp = &hsl[p2 * 512 + lane * 8];
                #pragma unroll
                for (int e = 0; e < 8; ++e) s += (float)v[e] * hp[e];
            }
        }
        #pragma unroll
        for (int off = 32; off > 0; off >>= 1) s += __shfl_xor(s, off);
        if (lane == 0) pl[w] = s;
    }
    __syncthreads();

    if (tid < 64) {
        float v = (lane < 32) ? pl[lane] : -3.4e38f;
        float m = v;
        #pragma unroll
        for (int off = 32; off > 0; off >>= 1) m = fmaxf(m, __shfl_xor(m, off));
        float e = (lane < 32) ? expf(v - m) : 0.f;
        float ssum = e;
        #pragma unroll
        for (int off = 32; off > 0; off >>= 1) ssum += __shfl_xor(ssum, off);
        if (lane < 32) pl[lane] = e / ssum;
    }
    __syncthreads();

    float a[8] = {0.f, 0.f, 0.f, 0.f, 0.f, 0.f, 0.f, 0.f};
    for (int w = 0; w < 32; ++w) {
        const int tw = t - 31 + w;
        if (tw >= 0) {
            const float pw = pl[w];
            half8 v = *(const half8*)(ring + ((size_t)(tw & 31) * B_ + b) * 2048 + tid * 8);
            #pragma unroll
            for (int e = 0; e < 8; ++e) a[e] += pw * (float)v[e];
        }
    }
    #pragma unroll
    for (int e = 0; e < 8; ++e) faH[b * 2048 + tid * 8 + e] = (_Float16)a[e];
}

// ---------------------------------------------------------------------------
// Persistent chunk, NORMAL launch (no cooperative API): 256 blocks x 256 thr,
// fully resident (1 block/CU; launch_bounds(256,2) caps VGPR<=256 so even
// 2/CU packing fits 160 KB LDS).  Per step: z0 -> gbar -> z1 -> gbar ->
// attn -> gbar.  Static LDS 49.8 KB.
// ---------------------------------------------------------------------------
struct ChunkArgs {
    const _Float16* Ec;
    const _Float16* M0T;
    const _Float16* M1T;
    const float* B0;
    const float* B1;
    float* c0;
    float* c1;
    _Float16* h0H;      // 2 parity buffers, 131072 halfs each
    _Float16* h1H;
    _Float16* faH;
    _Float16* ring;     // [32][128][2048]
    unsigned* flags;
    int t0;
};

__global__ __launch_bounds__(256, 2)
void recurrence_chunk(ChunkArgs a)
{
    __shared__ __align__(16) _Float16 As[2][128][72];
    __shared__ __align__(16) _Float16 Bs[2][16][72];
    __shared__ float hsl[2048];
    __shared__ float pl[32];

    const int bid = blockIdx.x;

    for (int s = 0; s < 32; ++s) {
        const int t = a.t0 + s;
        const unsigned tb = (unsigned)(t * 3);
        _Float16* ringSlot = a.ring + (size_t)(t & 31) * B_ * H_;
        const _Float16* h0p = a.h0H + (size_t)(t & 1) * 131072;
        _Float16*       h0c = a.h0H + (size_t)((t + 1) & 1) * 131072;
        const _Float16* h1p = a.h1H + (size_t)(t & 1) * 131072;
        _Float16*       h1c = a.h1H + (size_t)((t + 1) & 1) * 131072;
        const _Float16* Et  = a.Ec + (size_t)s * B_ * EMB_;

        // z0 = [E_t, fa, h0] @ M0 (K=3584), fused LSTM0
        lstm_gemm_body(As, Bs, bid, Et, 512, 512, a.faH, 2048, 2048,
                       h0p, 1024, 1024, a.M0T, 3584, a.B0, a.c0, h0c,
                       ringSlot, 0);
        gbar(a.flags, tb + 1);

        // z1 = [h0, h1] @ M1 (K=2048), fused LSTM1
        lstm_gemm_body(As, Bs, bid, h0c, 1024, 1024, h1p, 1024, 1024,
                       nullptr, 0, 0, a.M1T, 2048, a.B1, a.c1, h1c,
                       ringSlot, 1024);
        gbar(a.flags, tb + 2);

        // attention (blocks 0..127), writes faH for step t+1
        if (bid < 128)
            attn_body(hsl, pl, bid, a.ring, t, a.faH);
        gbar(a.flags, tb + 3);
    }
}

// ---------------------------------------------------------------------------
// Plain fp16 MFMA GEMM (emb + head).  mode 1: Cf=acc+bias; 2: relu->f16;
// 3: plain->f16.  (R3/R5-proven.)
// ---------------------------------------------------------------------------
__global__ __launch_bounds__(256)
void gemm_h(const _Float16* __restrict__ A0, int k0, int lda0,
            const _Float16* __restrict__ BT, int ldb,
            int N, int Ktot, int M,
            float* __restrict__ Cf, _Float16* __restrict__ Ch,
            const float* __restrict__ bias, int mode)
{
    __shared__ _Float16 As[64][40];
    __shared__ _Float16 Bs[64][40];

    const int tid = threadIdx.x;
    const int bn = blockIdx.x, bm = blockIdx.y;
    const int lane = tid & 63, wid = tid >> 6;
    const int wm = wid >> 1, wn = wid & 1;
    const int l15 = lane & 15, l4 = lane >> 4;
    const int ar = tid >> 2, ak = (tid & 3) * 8;

    f32x4 acc[2][2];
    #pragma unroll
    for (int i = 0; i < 2; ++i)
        #pragma unroll
        for (int j = 0; j < 2; ++j) acc[i][j] = (f32x4){0.f, 0.f, 0.f, 0.f};

    for (int kb = 0; kb < Ktot; kb += 32) {
        *(half8*)&As[ar][ak] =
            *(const half8*)(A0 + (size_t)(bm * 64 + ar) * lda0 + (kb + ak));
        *(half8*)&Bs[ar][ak] =
            *(const half8*)(BT + (size_t)(bn * 64 + ar) * ldb + (kb + ak));
        __syncthreads();

        half8 a0 = *(half8*)&As[wm * 32 + l15][l4 * 8];
        half8 a1 = *(half8*)&As[wm * 32 + 16 + l15][l4 * 8];
        half8 b0 = *(half8*)&Bs[wn * 32 + l15][l4 * 8];
        half8 b1 = *(half8*)&Bs[wn * 32 + 16 + l15][l4 * 8];
        acc[0][0] = MFMA16(a0, b0, acc[0][0]);
        acc[0][1] = MFMA16(a0, b1, acc[0][1]);
        acc[1][0] = MFMA16(a1, b0, acc[1][0]);
        acc[1][1] = MFMA16(a1, b1, acc[1][1]);
        __syncthreads();
    }

    const int colb = bn * 64 + wn * 32 + l15;
    const int rowb = bm * 64 + wm * 32 + l4 * 4;
    #pragma unroll
    for (int fm = 0; fm < 2; ++fm)
        #pragma unroll
        for (int fn = 0; fn < 2; ++fn) {
            const int cgc = colb + fn * 16;
            const int rg = rowb + fm * 16;
            const float bv = bias ? bias[cgc] : 0.f;
            #pragma unroll
            for (int j = 0; j < 4; ++j) {
                float v = acc[fm][fn][j] + bv;
                if (mode == 1)      Cf[(size_t)(rg + j) * N + cgc] = v;
                else if (mode == 2) Ch[(size_t)(rg + j) * N + cgc] = (_Float16)fmaxf(v, 0.f);
                else                Ch[(size_t)(rg + j) * N + cgc] = (_Float16)v;
            }
        }
}

// gatedH = (f16)(sigmoid(G) * hs)
__global__ __launch_bounds__(256)
void gate_epi(const _Float16* __restrict__ Gh, const _Float16* __restrict__ hsC,
              _Float16* __restrict__ gatedH)
{
    int idx = blockIdx.x * 256 + threadIdx.x;
    gatedH[idx] = (_Float16)(sigmoidf_((float)Gh[idx]) * (float)hsC[idx]);
}

// WT[n'][k] = (f16)W[k][n], zero-padded to Kp; gperm: n' = ((n&1023)<<2)|(n>>10)
__global__ __launch_bounds__(256)
void transpose_cast(const float* __restrict__ W, int K, int N,
                    _Float16* __restrict__ WT, int Kp, int gperm)
{
    __shared__ float tile[32][33];
    const int tx = threadIdx.x & 31, ty8 = threadIdx.x >> 5;
    const int k0 = blockIdx.y * 32, n0 = blockIdx.x * 32;
    for (int yy = ty8; yy < 32; yy += 8) {
        int k = k0 + yy;
        tile[yy][tx] = (k < K) ? W[(size_t)k * N + n0 + tx] : 0.f;
    }
    __syncthreads();
    for (int yy = ty8; yy < 32; yy += 8) {
        int n = n0 + yy;
        int nd = gperm ? (((n & 1023) << 2) | (n >> 10)) : n;
        WT[(size_t)nd * Kp + k0 + tx] = (_Float16)tile[tx][yy];
    }
}

// inpHc[r][0..287] = (f16)inp_chunk[r][0..257], zero-padded (4096 rows)
__global__ __launch_bounds__(256)
void cast_pad_inp(const float* __restrict__ inp, _Float16* __restrict__ inpH)
{
    int idx = blockIdx.x * 256 + threadIdx.x;
    int r = idx / 288, k = idx - r * 288;
    inpH[idx] = (k < 258) ? (_Float16)inp[(size_t)r * 258 + k] : (_Float16)0.f;
}

// ---------------------------------------------------------------------------
extern "C" void kernel_launch(void* const* d_in, const int* in_sizes, int n_in,
                              void* d_out, int out_size, void* d_ws, size_t ws_size,
                              hipStream_t stream)
{
    const float* inp  = (const float*)d_in[0];
    const float* embW = (const float*)d_in[1];
    const float* embB = (const float*)d_in[2];
    const float* M0   = (const float*)d_in[3];
    const float* B0   = (const float*)d_in[4];
    const float* M1   = (const float*)d_in[5];
    const float* B1   = (const float*)d_in[6];
    const float* Wg   = (const float*)d_in[7];
    const float* We   = (const float*)d_in[8];
    const float* be   = (const float*)d_in[9];
    const float* Wo   = (const float*)d_in[10];
    const float* bo   = (const float*)d_in[11];
    float* out = (float*)d_out;

    // ---- workspace (bytes), R5-proven layout + flags, total ~127.4 MB ----
    char* p = (char*)d_ws;
    float*    c0    = (float*)p;      p += 524288;
    float*    c1    = (float*)p;      p += 524288;
    _Float16* h0H   = (_Float16*)p;   p += 524288;   // 2 parity buffers
    _Float16* h1H   = (_Float16*)p;   p += 524288;
    _Float16* faH   = (_Float16*)p;   p += 524288;
    unsigned* flags = (unsigned*)p;   p += 4096;
    char* zero_base = (char*)c0; size_t zero_bytes = (size_t)(p - zero_base);
    _Float16* inpHc = (_Float16*)p;   p += (size_t)4096 * 288 * 2;
    _Float16* embWT = (_Float16*)p;   p += (size_t)512 * 288 * 2;
    _Float16* M0T   = (_Float16*)p;   p += (size_t)4096 * 3584 * 2;
    _Float16* M1T   = (_Float16*)p;   p += (size_t)4096 * 2048 * 2;
    _Float16* WgT   = (_Float16*)p;   p += (size_t)2048 * 2048 * 2;
    _Float16* WeT   = (_Float16*)p;   p += (size_t)1024 * 2048 * 2;
    _Float16* WoT   = (_Float16*)p;   p += (size_t)256 * 1024 * 2;
    _Float16* Ec    = (_Float16*)p;   p += (size_t)4096 * 512 * 2;
    _Float16* ring  = (_Float16*)p;   p += (size_t)32 * B_ * H_ * 2;
    _Float16* Gh    = (_Float16*)p;   p += (size_t)4096 * 2048 * 2;
    _Float16* gatedH= (_Float16*)p;   p += (size_t)4096 * 2048 * 2;
    _Float16* RH    = (_Float16*)p;   p += (size_t)4096 * 1024 * 2;
    if ((size_t)(p - (char*)d_ws) > ws_size) return;

    hipMemsetAsync(zero_base, 0, zero_bytes, stream);

    // one-time weight prep (M0/M1 gate-interleaved, row-major [4096][K])
    transpose_cast<<<dim3(16, 9),    256, 0, stream>>>(embW, 258, 512, embWT, 288, 0);
    transpose_cast<<<dim3(128, 112), 256, 0, stream>>>(M0, 3584, 4096, M0T, 3584, 1);
    transpose_cast<<<dim3(128, 64),  256, 0, stream>>>(M1, 2048, 4096, M1T, 2048, 1);
    transpose_cast<<<dim3(64, 64),   256, 0, stream>>>(Wg, 2048, 2048, WgT, 2048, 0);
    transpose_cast<<<dim3(32, 64),   256, 0, stream>>>(We, 2048, 1024, WeT, 2048, 0);
    transpose_cast<<<dim3(8, 32),    256, 0, stream>>>(Wo, 1024, 256,  WoT, 1024, 0);

    for (int cch = 0; cch < 8; ++cch) {
        const int t0 = cch * 32;

        // embed this chunk
        cast_pad_inp<<<4608, 256, 0, stream>>>(inp + (size_t)t0 * B_ * 258, inpHc);
        gemm_h<<<dim3(8, 64), 256, 0, stream>>>(
            inpHc, 288, 288, embWT, 288, 512, 288, 4096, nullptr, Ec, embB, 3);

        // 32 recurrence steps: one PLAIN persistent launch, flag barriers
        ChunkArgs ca;
        ca.Ec = Ec; ca.M0T = M0T; ca.M1T = M1T; ca.B0 = B0; ca.B1 = B1;
        ca.c0 = c0; ca.c1 = c1; ca.h0H = h0H; ca.h1H = h1H;
        ca.faH = faH; ca.ring = ring; ca.flags = flags; ca.t0 = t0;
        recurrence_chunk<<<dim3(256), dim3(256), 0, stream>>>(ca);

        // batched head over the chunk (ring slots 0..31 == steps t0..t0+31)
        gemm_h<<<dim3(32, 64), 256, 0, stream>>>(
            ring, 2048, 2048, WgT, 2048, 2048, 2048, 4096, nullptr, Gh, nullptr, 3);
        gate_epi<<<32768, 256, 0, stream>>>(Gh, ring, gatedH);
        gemm_h<<<dim3(16, 64), 256, 0, stream>>>(
            gatedH, 2048, 2048, WeT, 2048, 1024, 2048, 4096, nullptr, RH, be, 2);
        gemm_h<<<dim3(4, 64), 256, 0, stream>>>(
            RH, 1024, 1024, WoT, 1024, 256, 1024, 4096,
            out + (size_t)cch * 32 * B_ * VOC_, nullptr, bo, 1);
    }
}

// Round 12
// 77814.813 us; speedup vs baseline: 1.3325x; 1.3325x over previous
//
#include <hip/hip_runtime.h>
#include <hip/hip_bf16.h>
#include <math.h>

#define T_ 256
#define B_ 128
#define VOC_ 256
#define EMB_ 512
#define N_ 1024
#define H_ 2048
#define WIN_ 32
#define OUT_EMB_ 1024

typedef _Float16 half8 __attribute__((ext_vector_type(8)));
typedef float f32x4 __attribute__((ext_vector_type(4)));

__device__ __forceinline__ float sigmoidf_(float x) { return 1.f / (1.f + expf(-x)); }

#define MFMA16(A, B, C) __builtin_amdgcn_mfma_f32_16x16x32_f16((A), (B), (C), 0, 0, 0)

// ---------------------------------------------------------------------------
// Grid barrier, single-poller counter form (R11's fence structure, new spin
// ownership).  ctr zeroed once per call; n = global barrier ordinal (strictly
// increasing); wait until 256*n arrivals.  Only thread 0 touches memory in
// the spin; waves 1..3 park in s_barrier.
// ---------------------------------------------------------------------------
__device__ __forceinline__ void gbar(unsigned* ctr, unsigned n)
{
    __syncthreads();
    __threadfence();                      // publish this block's writes
    if (threadIdx.x == 0) {
        __hip_atomic_fetch_add(ctr, 1u, __ATOMIC_ACQ_REL, __HIP_MEMORY_SCOPE_AGENT);
        const unsigned tgt = n * 256u;
        while (__hip_atomic_load(ctr, __ATOMIC_ACQUIRE, __HIP_MEMORY_SCOPE_AGENT) < tgt)
            __builtin_amdgcn_s_sleep(2);
    }
    __syncthreads();
    __threadfence();                      // discard stale cached lines
}

// ---------------------------------------------------------------------------
// LSTM gate epilogue (R11-proven): lanes (l15&3)==0 own j; neighbor lanes
// hold the f,i,o,m quad, exchanged via shfl_xor.
// ---------------------------------------------------------------------------
__device__ __forceinline__ void lstm_epi(f32x4 acc, int rbase, bool owner, int jglob,
                                         float bfv, float biv, float bov, float bmv,
                                         float* __restrict__ c, _Float16* __restrict__ h,
                                         _Float16* __restrict__ ringSlot, int rhalf)
{
    #pragma unroll
    for (int jr = 0; jr < 4; ++jr) {
        float v  = acc[jr];
        float v1 = __shfl_xor(v, 1);
        float v2 = __shfl_xor(v, 2);
        float v3 = __shfl_xor(v, 3);
        if (owner) {
            const int row = rbase + jr;
            float f  = sigmoidf_(v  + bfv);
            float ii = sigmoidf_(v1 + biv);
            float o  = sigmoidf_(v2 + bov);
            float m  = tanhf(v3 + bmv);
            const int ci = row * 1024 + jglob;
            float cn = c[ci] * f + m * ii;
            float hn = tanhf(cn) * o;
            c[ci] = cn;
            h[ci] = (_Float16)hn;
            ringSlot[row * 2048 + rhalf + jglob] = (_Float16)hn;
        }
    }
}

// ---------------------------------------------------------------------------
// z0 fused LSTM GEMM with LDS-PINNED B (this block's 16 M0 rows live in M0s
// for the whole chunk; padded row stride 3592 halfs -> 2-way bank alias,
// free).  A-staging pipeline identical to R11's proven schedule, minus B.
// ---------------------------------------------------------------------------
__device__ __forceinline__
void lstm_gemm_pinnedB(_Float16 (*As)[128][72], const _Float16* __restrict__ M0s,
                       int bn,
                       const _Float16* __restrict__ A0, int k0, int lda0,
                       const _Float16* __restrict__ A1, int k1, int lda1,
                       const _Float16* __restrict__ A2, int k2, int lda2,
                       int Ktot,
                       const float* __restrict__ bias,
                       float* __restrict__ c, _Float16* __restrict__ hH,
                       _Float16* __restrict__ ringSlot, int ringHalf)
{
    const int tid = threadIdx.x;
    const int l = tid & 63, w = tid >> 6;
    const int l15 = l & 15, kg = l >> 4;

    const int arow = tid >> 2, akh = (tid & 3) * 16;
    const int NIT = Ktot >> 6;           // 56

    f32x4 ac0 = {0.f, 0.f, 0.f, 0.f}, ac1 = {0.f, 0.f, 0.f, 0.f};
    half8 a0A, a1A, a2A, a3A, a0B, a1B, a2B, a3B;

    auto issue = [&](int it, half8& r0, half8& r1, half8& r2, half8& r3) {
        const int kb = it * 64;
        const _Float16* Ag; int so, ld;
        if (kb < k0)           { Ag = A0; so = 0;       ld = lda0; }
        else if (kb < k0 + k1) { Ag = A1; so = k0;      ld = lda1; }
        else                   { Ag = A2; so = k0 + k1; ld = lda2; }
        const _Float16* ap  = Ag + (size_t)arow * ld + (kb - so);
        const _Float16* ap2 = Ag + (size_t)(arow + 64) * ld + (kb - so);
        r0 = *(const half8*)(ap + akh);
        r1 = *(const half8*)(ap + akh + 8);
        r2 = *(const half8*)(ap2 + akh);
        r3 = *(const half8*)(ap2 + akh + 8);
    };
    auto wlds = [&](int buf, half8 r0, half8 r1, half8 r2, half8 r3) {
        *(half8*)&As[buf][arow][akh]          = r0;
        *(half8*)&As[buf][arow][akh + 8]      = r1;
        *(half8*)&As[buf][arow + 64][akh]     = r2;
        *(half8*)&As[buf][arow + 64][akh + 8] = r3;
    };
    auto comp = [&](int buf, int kb) {
        #pragma unroll
        for (int ks = 0; ks < 2; ++ks) {
            half8 a0v = *(half8*)&As[buf][w * 32 + l15][ks * 32 + kg * 8];
            half8 a1v = *(half8*)&As[buf][w * 32 + 16 + l15][ks * 32 + kg * 8];
            half8 b0v = *(const half8*)&M0s[l15 * 3592 + kb + ks * 32 + kg * 8];
            ac0 = MFMA16(a0v, b0v, ac0);
            ac1 = MFMA16(a1v, b0v, ac1);
        }
    };

    issue(0, a0A, a1A, a2A, a3A);
    issue(1, a0B, a1B, a2B, a3B);
    wlds(0, a0A, a1A, a2A, a3A);
    __syncthreads();

    for (int it = 0; it < NIT; it += 2) {
        comp(0, it * 64);
        if (it + 2 < NIT) issue(it + 2, a0A, a1A, a2A, a3A);
        __syncthreads();
        wlds(1, a0B, a1B, a2B, a3B);
        __syncthreads();
        comp(1, (it + 1) * 64);
        if (it + 3 < NIT) issue(it + 3, a0B, a1B, a2B, a3B);
        __syncthreads();
        if (it + 2 < NIT) wlds(0, a0A, a1A, a2A, a3A);
        __syncthreads();
    }

    const int cgl = bn * 16 + l15;
    const bool owner = (cgl & 3) == 0;
    const int jglob = cgl >> 2;
    float bf = 0.f, bi = 0.f, bo_ = 0.f, bm_ = 0.f;
    if (owner) {
        bf  = bias[jglob];
        bi  = bias[1024 + jglob];
        bo_ = bias[2048 + jglob];
        bm_ = bias[3072 + jglob];
    }
    lstm_epi(ac0, w * 32 + kg * 4,      owner, jglob, bf, bi, bo_, bm_,
             c, hH, ringSlot, ringHalf);
    lstm_epi(ac1, w * 32 + 16 + kg * 4, owner, jglob, bf, bi, bo_, bm_,
             c, hH, ringSlot, ringHalf);
}

// ---------------------------------------------------------------------------
// z1 fused LSTM GEMM, R11-proven verbatim (streamed B, M1 slice is L2-hot).
// ---------------------------------------------------------------------------
__device__ __forceinline__
void lstm_gemm_body(_Float16 (*As)[128][72], _Float16 (*Bs)[16][72], int bn,
                    const _Float16* __restrict__ A0, int k0, int lda0,
                    const _Float16* __restrict__ A1, int k1, int lda1,
                    const _Float16* __restrict__ WT, int Ktot,
                    const float* __restrict__ bias,
                    float* __restrict__ c, _Float16* __restrict__ hH,
                    _Float16* __restrict__ ringSlot, int ringHalf)
{
    const int tid = threadIdx.x;
    const int l = tid & 63, w = tid >> 6;
    const int l15 = l & 15, kg = l >> 4;

    const int arow = tid >> 2, akh = (tid & 3) * 16;
    const int brow = (tid >> 3) & 15, bkh = (tid & 7) * 8;
    const _Float16* Bg = WT + (size_t)(bn * 16 + brow) * Ktot;

    const int NIT = Ktot >> 6;           // 32

    f32x4 ac0 = {0.f, 0.f, 0.f, 0.f}, ac1 = {0.f, 0.f, 0.f, 0.f};
    half8 a0A, a1A, a2A, a3A, bA, a0B, a1B, a2B, a3B, bB;

    auto issue = [&](int it, half8& r0, half8& r1, half8& r2, half8& r3, half8& rb) {
        const int kb = it * 64;
        const _Float16* Ag; int so, ld;
        if (kb < k0) { Ag = A0; so = 0;  ld = lda0; }
        else         { Ag = A1; so = k0; ld = lda1; }
        const _Float16* ap  = Ag + (size_t)arow * ld + (kb - so);
        const _Float16* ap2 = Ag + (size_t)(arow + 64) * ld + (kb - so);
        r0 = *(const half8*)(ap + akh);
        r1 = *(const half8*)(ap + akh + 8);
        r2 = *(const half8*)(ap2 + akh);
        r3 = *(const half8*)(ap2 + akh + 8);
        if (tid < 128) rb = *(const half8*)(Bg + kb + bkh);
    };
    auto wlds = [&](int buf, half8 r0, half8 r1, half8 r2, half8 r3, half8 rb) {
        *(half8*)&As[buf][arow][akh]          = r0;
        *(half8*)&As[buf][arow][akh + 8]      = r1;
        *(half8*)&As[buf][arow + 64][akh]     = r2;
        *(half8*)&As[buf][arow + 64][akh + 8] = r3;
        if (tid < 128) *(half8*)&Bs[buf][brow][bkh] = rb;
    };
    auto comp = [&](int buf) {
        #pragma unroll
        for (int ks = 0; ks < 2; ++ks) {
            half8 a0 = *(half8*)&As[buf][w * 32 + l15][ks * 32 + kg * 8];
            half8 a1 = *(half8*)&As[buf][w * 32 + 16 + l15][ks * 32 + kg * 8];
            half8 b0 = *(half8*)&Bs[buf][l15][ks * 32 + kg * 8];
            ac0 = MFMA16(a0, b0, ac0);
            ac1 = MFMA16(a1, b0, ac1);
        }
    };

    issue(0, a0A, a1A, a2A, a3A, bA);
    issue(1, a0B, a1B, a2B, a3B, bB);
    wlds(0, a0A, a1A, a2A, a3A, bA);
    __syncthreads();

    for (int it = 0; it < NIT; it += 2) {
        comp(0);
        if (it + 2 < NIT) issue(it + 2, a0A, a1A, a2A, a3A, bA);
        __syncthreads();
        wlds(1, a0B, a1B, a2B, a3B, bB);
        __syncthreads();
        comp(1);
        if (it + 3 < NIT) issue(it + 3, a0B, a1B, a2B, a3B, bB);
        __syncthreads();
        if (it + 2 < NIT) wlds(0, a0A, a1A, a2A, a3A, bA);
        __syncthreads();
    }

    const int cgl = bn * 16 + l15;
    const bool owner = (cgl & 3) == 0;
    const int jglob = cgl >> 2;
    float bf = 0.f, bi = 0.f, bo_ = 0.f, bm_ = 0.f;
    if (owner) {
        bf  = bias[jglob];
        bi  = bias[1024 + jglob];
        bo_ = bias[2048 + jglob];
        bm_ = bias[3072 + jglob];
    }
    lstm_epi(ac0, w * 32 + kg * 4,      owner, jglob, bf, bi, bo_, bm_,
             c, hH, ringSlot, ringHalf);
    lstm_epi(ac1, w * 32 + 16 + kg * 4, owner, jglob, bf, bi, bo_, bm_,
             c, hH, ringSlot, ringHalf);
}

// ---------------------------------------------------------------------------
// Attention body (R11-proven). Ring layout [slot][b][2048].
// ---------------------------------------------------------------------------
__device__ __forceinline__ void attn_body(float* hsl, float* pl, int b,
                                          const _Float16* __restrict__ ring, int t,
                                          _Float16* __restrict__ faH)
{
    const int tid = threadIdx.x;
    const _Float16* hs = ring + ((size_t)(t & 31) * B_ + b) * 2048;
    {
        half8 v = *(const half8*)(hs + tid * 8);
        #pragma unroll
        for (int e = 0; e < 8; ++e) hsl[tid * 8 + e] = (float)v[e];
    }
    __syncthreads();

    const int wv = tid >> 6, lane = tid & 63;
    #pragma unroll
    for (int w8 = 0; w8 < 8; ++w8) {
        const int w = wv * 8 + w8;
        const int tw = t - 31 + w;
        float s = 0.f;
        if (tw >= 0) {
            const _Float16* br = ring + ((size_t)(tw & 31) * B_ + b) * 2048;
            #pragma unroll
            for (int p2 = 0; p2 < 4; ++p2) {
                half8 v = *(const half8*)(br + p2 * 512 + lane * 8);
                const float* hp = &hsl[p2 * 512 + lane * 8];
                #pragma unroll
                for (int e = 0; e < 8; ++e) s += (float)v[e] * hp[e];
            }
        }
        #pragma unroll
        for (int off = 32; off > 0; off >>= 1) s += __shfl_xor(s, off);
        if (lane == 0) pl[w] = s;
    }
    __syncthreads();

    if (tid < 64) {
        float v = (lane < 32) ? pl[lane] : -3.4e38f;
        float m = v;
        #pragma unroll
        for (int off = 32; off > 0; off >>= 1) m = fmaxf(m, __shfl_xor(m, off));
        float e = (lane < 32) ? expf(v - m) : 0.f;
        float ssum = e;
        #pragma unroll
        for (int off = 32; off > 0; off >>= 1) ssum += __shfl_xor(ssum, off);
        if (lane < 32) pl[lane] = e / ssum;
    }
    __syncthreads();

    float a[8] = {0.f, 0.f, 0.f, 0.f, 0.f, 0.f, 0.f, 0.f};
    for (int w = 0; w < 32; ++w) {
        const int tw = t - 31 + w;
        if (tw >= 0) {
            const float pw = pl[w];
            half8 v = *(const half8*)(ring + ((size_t)(tw & 31) * B_ + b) * 2048 + tid * 8);
            #pragma unroll
            for (int e = 0; e < 8; ++e) a[e] += pw * (float)v[e];
        }
    }
    #pragma unroll
    for (int e = 0; e < 8; ++e) faH[b * 2048 + tid * 8 + e] = (_Float16)a[e];
}

// ---------------------------------------------------------------------------
// Persistent chunk, plain launch (R11-proven path): 256 blocks x 256 thr,
// 1 block/CU (forced by 152.7 KB static LDS).  M0 slice pinned in LDS for
// the whole chunk.  Per step: z0 -> gbar -> z1 -> gbar -> attn -> gbar.
// ---------------------------------------------------------------------------
struct ChunkArgs {
    const _Float16* Ec;
    const _Float16* M0T;   // [4096][3584] gate-interleaved
    const _Float16* M1T;   // [4096][2048] gate-interleaved
    const float* B0;
    const float* B1;
    float* c0;
    float* c1;
    _Float16* h0H;         // 2 parity buffers, 131072 halfs each
    _Float16* h1H;
    _Float16* faH;
    _Float16* ring;        // [32][128][2048]
    unsigned* ctr;
    int t0;
};

__global__ __launch_bounds__(256)
void recurrence_chunk(ChunkArgs a)
{
    __shared__ __align__(16) _Float16 M0s[16 * 3592];   // 114,944 B (padded rows)
    __shared__ __align__(16) _Float16 As[2][128][72];   //  36,864 B
    __shared__ __align__(16) _Float16 Bs[2][16][72];    //   4,608 B

    const int tid = threadIdx.x, bid = blockIdx.x;

    // pin this block's M0 slice (rows bid*16 .. +15) into LDS, once per chunk
    {
        const _Float16* src = a.M0T + (size_t)bid * 16 * 3584;
        for (int u = tid; u < 7168; u += 256) {          // 16*3584/8
            int row = u / 448, c8 = u - row * 448;
            *(half8*)&M0s[row * 3592 + c8 * 8] =
                *(const half8*)(src + (size_t)row * 3584 + c8 * 8);
        }
        __syncthreads();
    }

    for (int s = 0; s < 32; ++s) {
        const int t = a.t0 + s;
        const unsigned nb = (unsigned)(t * 3);           // global barrier ordinal base
        _Float16* ringSlot = a.ring + (size_t)(t & 31) * B_ * H_;
        const _Float16* h0p = a.h0H + (size_t)(t & 1) * 131072;
        _Float16*       h0c = a.h0H + (size_t)((t + 1) & 1) * 131072;
        const _Float16* h1p = a.h1H + (size_t)(t & 1) * 131072;
        _Float16*       h1c = a.h1H + (size_t)((t + 1) & 1) * 131072;
        const _Float16* Et  = a.Ec + (size_t)s * B_ * EMB_;

        // z0 = [E_t, fa, h0] @ M0 (K=3584), B pinned in LDS
        lstm_gemm_pinnedB(As, M0s, bid, Et, 512, 512, a.faH, 2048, 2048,
                          h0p, 1024, 1024, 3584, a.B0, a.c0, h0c, ringSlot, 0);
        gbar(a.ctr, nb + 1);

        // z1 = [h0, h1] @ M1 (K=2048), B streamed (L2-hot)
        lstm_gemm_body(As, Bs, bid, h0c, 1024, 1024, h1p, 1024, 1024,
                       a.M1T, 2048, a.B1, a.c1, h1c, ringSlot, 1024);
        gbar(a.ctr, nb + 2);

        // attention (blocks 0..127); LDS aliased onto As
        if (bid < 128)
            attn_body((float*)&As[0][0][0], (float*)&As[0][0][0] + 2048,
                      bid, a.ring, t, a.faH);
        gbar(a.ctr, nb + 3);
    }
}

// ---------------------------------------------------------------------------
// Plain fp16 MFMA GEMM (emb + head).  mode 1: Cf=acc+bias; 2: relu->f16;
// 3: plain->f16.  (R3/R11-proven.)
// ---------------------------------------------------------------------------
__global__ __launch_bounds__(256)
void gemm_h(const _Float16* __restrict__ A0, int k0, int lda0,
            const _Float16* __restrict__ BT, int ldb,
            int N, int Ktot, int M,
            float* __restrict__ Cf, _Float16* __restrict__ Ch,
            const float* __restrict__ bias, int mode)
{
    __shared__ _Float16 As[64][40];
    __shared__ _Float16 Bs[64][40];

    const int tid = threadIdx.x;
    const int bn = blockIdx.x, bm = blockIdx.y;
    const int lane = tid & 63, wid = tid >> 6;
    const int wm = wid >> 1, wn = wid & 1;
    const int l15 = lane & 15, l4 = lane >> 4;
    const int ar = tid >> 2, ak = (tid & 3) * 8;

    f32x4 acc[2][2];
    #pragma unroll
    for (int i = 0; i < 2; ++i)
        #pragma unroll
        for (int j = 0; j < 2; ++j) acc[i][j] = (f32x4){0.f, 0.f, 0.f, 0.f};

    for (int kb = 0; kb < Ktot; kb += 32) {
        *(half8*)&As[ar][ak] =
            *(const half8*)(A0 + (size_t)(bm * 64 + ar) * lda0 + (kb + ak));
        *(half8*)&Bs[ar][ak] =
            *(const half8*)(BT + (size_t)(bn * 64 + ar) * ldb + (kb + ak));
        __syncthreads();

        half8 a0 = *(half8*)&As[wm * 32 + l15][l4 * 8];
        half8 a1 = *(half8*)&As[wm * 32 + 16 + l15][l4 * 8];
        half8 b0 = *(half8*)&Bs[wn * 32 + l15][l4 * 8];
        half8 b1 = *(half8*)&Bs[wn * 32 + 16 + l15][l4 * 8];
        acc[0][0] = MFMA16(a0, b0, acc[0][0]);
        acc[0][1] = MFMA16(a0, b1, acc[0][1]);
        acc[1][0] = MFMA16(a1, b0, acc[1][0]);
        acc[1][1] = MFMA16(a1, b1, acc[1][1]);
        __syncthreads();
    }

    const int colb = bn * 64 + wn * 32 + l15;
    const int rowb = bm * 64 + wm * 32 + l4 * 4;
    #pragma unroll
    for (int fm = 0; fm < 2; ++fm)
        #pragma unroll
        for (int fn = 0; fn < 2; ++fn) {
            const int cgc = colb + fn * 16;
            const int rg = rowb + fm * 16;
            const float bv = bias ? bias[cgc] : 0.f;
            #pragma unroll
            for (int j = 0; j < 4; ++j) {
                float v = acc[fm][fn][j] + bv;
                if (mode == 1)      Cf[(size_t)(rg + j) * N + cgc] = v;
                else if (mode == 2) Ch[(size_t)(rg + j) * N + cgc] = (_Float16)fmaxf(v, 0.f);
                else                Ch[(size_t)(rg + j) * N + cgc] = (_Float16)v;
            }
        }
}

// gatedH = (f16)(sigmoid(G) * hs)
__global__ __launch_bounds__(256)
void gate_epi(const _Float16* __restrict__ Gh, const _Float16* __restrict__ hsC,
              _Float16* __restrict__ gatedH)
{
    int idx = blockIdx.x * 256 + threadIdx.x;
    gatedH[idx] = (_Float16)(sigmoidf_((float)Gh[idx]) * (float)hsC[idx]);
}

// WT[n'][k] = (f16)W[k][n], zero-padded to Kp; gperm: n' = ((n&1023)<<2)|(n>>10)
__global__ __launch_bounds__(256)
void transpose_cast(const float* __restrict__ W, int K, int N,
                    _Float16* __restrict__ WT, int Kp, int gperm)
{
    __shared__ float tile[32][33];
    const int tx = threadIdx.x & 31, ty8 = threadIdx.x >> 5;
    const int k0 = blockIdx.y * 32, n0 = blockIdx.x * 32;
    for (int yy = ty8; yy < 32; yy += 8) {
        int k = k0 + yy;
        tile[yy][tx] = (k < K) ? W[(size_t)k * N + n0 + tx] : 0.f;
    }
    __syncthreads();
    for (int yy = ty8; yy < 32; yy += 8) {
        int n = n0 + yy;
        int nd = gperm ? (((n & 1023) << 2) | (n >> 10)) : n;
        WT[(size_t)nd * Kp + k0 + tx] = (_Float16)tile[tx][yy];
    }
}

// inpHc[r][0..287] = (f16)inp_chunk[r][0..257], zero-padded (4096 rows)
__global__ __launch_bounds__(256)
void cast_pad_inp(const float* __restrict__ inp, _Float16* __restrict__ inpH)
{
    int idx = blockIdx.x * 256 + threadIdx.x;
    int r = idx / 288, k = idx - r * 288;
    inpH[idx] = (k < 258) ? (_Float16)inp[(size_t)r * 258 + k] : (_Float16)0.f;
}

// ---------------------------------------------------------------------------
extern "C" void kernel_launch(void* const* d_in, const int* in_sizes, int n_in,
                              void* d_out, int out_size, void* d_ws, size_t ws_size,
                              hipStream_t stream)
{
    const float* inp  = (const float*)d_in[0];
    const float* embW = (const float*)d_in[1];
    const float* embB = (const float*)d_in[2];
    const float* M0   = (const float*)d_in[3];
    const float* B0   = (const float*)d_in[4];
    const float* M1   = (const float*)d_in[5];
    const float* B1   = (const float*)d_in[6];
    const float* Wg   = (const float*)d_in[7];
    const float* We   = (const float*)d_in[8];
    const float* be   = (const float*)d_in[9];
    const float* Wo   = (const float*)d_in[10];
    const float* bo   = (const float*)d_in[11];
    float* out = (float*)d_out;

    // ---- workspace (bytes), R11-proven layout, total ~127.4 MB ----
    char* p = (char*)d_ws;
    float*    c0    = (float*)p;      p += 524288;
    float*    c1    = (float*)p;      p += 524288;
    _Float16* h0H   = (_Float16*)p;   p += 524288;   // 2 parity buffers
    _Float16* h1H   = (_Float16*)p;   p += 524288;
    _Float16* faH   = (_Float16*)p;   p += 524288;
    unsigned* ctr   = (unsigned*)p;   p += 4096;
    char* zero_base = (char*)c0; size_t zero_bytes = (size_t)(p - zero_base);
    _Float16* inpHc = (_Float16*)p;   p += (size_t)4096 * 288 * 2;
    _Float16* embWT = (_Float16*)p;   p += (size_t)512 * 288 * 2;
    _Float16* M0T   = (_Float16*)p;   p += (size_t)4096 * 3584 * 2;
    _Float16* M1T   = (_Float16*)p;   p += (size_t)4096 * 2048 * 2;
    _Float16* WgT   = (_Float16*)p;   p += (size_t)2048 * 2048 * 2;
    _Float16* WeT   = (_Float16*)p;   p += (size_t)1024 * 2048 * 2;
    _Float16* WoT   = (_Float16*)p;   p += (size_t)256 * 1024 * 2;
    _Float16* Ec    = (_Float16*)p;   p += (size_t)4096 * 512 * 2;
    _Float16* ring  = (_Float16*)p;   p += (size_t)32 * B_ * H_ * 2;
    _Float16* Gh    = (_Float16*)p;   p += (size_t)4096 * 2048 * 2;
    _Float16* gatedH= (_Float16*)p;   p += (size_t)4096 * 2048 * 2;
    _Float16* RH    = (_Float16*)p;   p += (size_t)4096 * 1024 * 2;
    if ((size_t)(p - (char*)d_ws) > ws_size) return;

    hipMemsetAsync(zero_base, 0, zero_bytes, stream);

    // one-time weight prep (M0/M1 gate-interleaved, row-major [4096][K])
    transpose_cast<<<dim3(16, 9),    256, 0, stream>>>(embW, 258, 512, embWT, 288, 0);
    transpose_cast<<<dim3(128, 112), 256, 0, stream>>>(M0, 3584, 4096, M0T, 3584, 1);
    transpose_cast<<<dim3(128, 64),  256, 0, stream>>>(M1, 2048, 4096, M1T, 2048, 1);
    transpose_cast<<<dim3(64, 64),   256, 0, stream>>>(Wg, 2048, 2048, WgT, 2048, 0);
    transpose_cast<<<dim3(32, 64),   256, 0, stream>>>(We, 2048, 1024, WeT, 2048, 0);
    transpose_cast<<<dim3(8, 32),    256, 0, stream>>>(Wo, 1024, 256,  WoT, 1024, 0);

    for (int cch = 0; cch < 8; ++cch) {
        const int t0 = cch * 32;

        // embed this chunk
        cast_pad_inp<<<4608, 256, 0, stream>>>(inp + (size_t)t0 * B_ * 258, inpHc);
        gemm_h<<<dim3(8, 64), 256, 0, stream>>>(
            inpHc, 288, 288, embWT, 288, 512, 288, 4096, nullptr, Ec, embB, 3);

        // 32 recurrence steps: one PLAIN persistent launch, counter barriers
        ChunkArgs ca;
        ca.Ec = Ec; ca.M0T = M0T; ca.M1T = M1T; ca.B0 = B0; ca.B1 = B1;
        ca.c0 = c0; ca.c1 = c1; ca.h0H = h0H; ca.h1H = h1H;
        ca.faH = faH; ca.ring = ring; ca.ctr = ctr; ca.t0 = t0;
        recurrence_chunk<<<dim3(256), dim3(256), 0, stream>>>(ca);

        // batched head over the chunk (ring slots 0..31 == steps t0..t0+31)
        gemm_h<<<dim3(32, 64), 256, 0, stream>>>(
            ring, 2048, 2048, WgT, 2048, 2048, 2048, 4096, nullptr, Gh, nullptr, 3);
        gate_epi<<<32768, 256, 0, stream>>>(Gh, ring, gatedH);
        gemm_h<<<dim3(16, 64), 256, 0, stream>>>(
            gatedH, 2048, 2048, WeT, 2048, 1024, 2048, 4096, nullptr, RH, be, 2);
        gemm_h<<<dim3(4, 64), 256, 0, stream>>>(
            RH, 1024, 1024, WoT, 1024, 256, 1024, 4096,
            out + (size_t)cch * 32 * B_ * VOC_, nullptr, bo, 1);
    }
}